// Round 13
// baseline (588.427 us; speedup 1.0000x reference)
//
#include <hip/hip_runtime.h>

// ---------------------------------------------------------------------------
// SABlock round 13: (a) GEMM K-loops double-buffered (one barrier/iter, was
// two -- attacks the documented barrier-drain stall; same math/layout);
// (b) cls q0/ms/logits/reduce fused into one kernel with bit-identical fp64
// partitions (3 fewer launches). Base: round 12 (467 us, passing).
// ---------------------------------------------------------------------------

#define B_  4
#define N_  1025
#define C_  768
#define H_  12
#define D_  64
#define M_TOT (B_ * N_)      // 4100
#define M_PAD 4224           // 33 * 128
#define KEXP 2304            // 3 * 768
#define NPAD 1088            // 17 * 64

#define OFF_EIND 3148800
#define OFF_EIDX 3465216
#define OFF_FIND 3465628
#define OFF_FIDX 3782044
#define OFF_CLS  3782456

// workspace offsets (floats)
#define WS_F64   0
#define WS_XS    196608      // ushort[4224*2304]  x' A-pattern; later ctx'
#define WS_QKVB  5062656     // ushort[2304*2304]
#define WS_OUTB  7716864     // ushort[768*2304]
#define WS_QE    8601600     // ushort[4*12*1088*128]
#define WS_KE    11943936
#define WS_VT    15286272

// double-region layout (indices into double*)
#define DQ0 0
#define DMS 3072
#define DLG 39936
#define DMX 89136
#define DZ  89184

// splitter work partition
#define SPLIT_A_ITEMS (M_PAD * 192)          // 811008
#define SPLIT_B1_ITEMS (2304 * 192)          // 442368
#define SPLIT_B2_ITEMS (768 * 192)           // 147456
#define SPLIT_TOTAL (SPLIT_A_ITEMS + SPLIT_B1_ITEMS + SPLIT_B2_ITEMS)

typedef short s16x8 __attribute__((ext_vector_type(8)));
typedef float f32x4 __attribute__((ext_vector_type(4)));

__device__ inline unsigned short f2bf(float f) {
    unsigned u = __float_as_uint(f);
    u += 0x7FFF + ((u >> 16) & 1);          // RNE to bf16
    return (unsigned short)(u >> 16);
}
__device__ inline float bf2f(unsigned short h) {
    return __uint_as_float(((unsigned)h) << 16);
}

// async global->LDS, 16 bytes/lane; LDS dest = wave-uniform base + lane*16
__device__ __forceinline__ void gl2lds16(const unsigned short* g, unsigned short* l) {
    __builtin_amdgcn_global_load_lds(
        (const __attribute__((address_space(1))) unsigned int*)g,
        (__attribute__((address_space(3))) unsigned int*)l,
        16, 0, 0);
}

// grouped swizzle: 8-wide m super-rows, n fastest inside a super-row
__device__ inline void gemm_decode(int lid, int NT, int& m, int& n) {
    int gi = lid / (8 * NT);
    int r  = lid % (8 * NT);
    int base = gi * 8;
    int gsize = (33 - base < 8) ? (33 - base) : 8;
    n = r / gsize;
    m = base + r % gsize;
}

// ---------------------------------------------------------------------------
// Merged splitter: A-pattern for x, B-pattern for w_qkv and w_out.
// ---------------------------------------------------------------------------
__global__ __launch_bounds__(256) void split_all_kernel(
    const float* __restrict__ x, const float* __restrict__ w_qkv,
    const float* __restrict__ w_out,
    unsigned short* __restrict__ xs, unsigned short* __restrict__ qkvB,
    unsigned short* __restrict__ outB)
{
    int idx = blockIdx.x * 256 + threadIdx.x;
    if (idx < SPLIT_A_ITEMS) {
        int m = idx / 192, c4 = (idx - m * 192) * 4;
        ushort4 hi = make_ushort4(0,0,0,0), lo = hi;
        if (m < M_TOT) {
            float4 f = *(const float4*)&x[(size_t)m * C_ + c4];
            hi.x = f2bf(f.x); hi.y = f2bf(f.y); hi.z = f2bf(f.z); hi.w = f2bf(f.w);
            lo.x = f2bf(f.x - bf2f(hi.x)); lo.y = f2bf(f.y - bf2f(hi.y));
            lo.z = f2bf(f.z - bf2f(hi.z)); lo.w = f2bf(f.w - bf2f(hi.w));
        }
        unsigned short* d = xs + (size_t)m * KEXP + c4;
        *(ushort4*)(d)        = hi;
        *(ushort4*)(d + 768)  = hi;
        *(ushort4*)(d + 1536) = lo;
        return;
    }
    idx -= SPLIT_A_ITEMS;
    const float* src;
    unsigned short* dst;
    if (idx < SPLIT_B1_ITEMS) { src = w_qkv; dst = qkvB; }
    else { idx -= SPLIT_B1_ITEMS; if (idx >= SPLIT_B2_ITEMS) return; src = w_out; dst = outB; }
    int m = idx / 192, c4 = (idx - m * 192) * 4;
    float4 f = *(const float4*)&src[(size_t)m * C_ + c4];
    ushort4 hi, lo;
    hi.x = f2bf(f.x); hi.y = f2bf(f.y); hi.z = f2bf(f.z); hi.w = f2bf(f.w);
    lo.x = f2bf(f.x - bf2f(hi.x)); lo.y = f2bf(f.y - bf2f(hi.y));
    lo.z = f2bf(f.z - bf2f(hi.z)); lo.w = f2bf(f.w - bf2f(hi.w));
    unsigned short* d = dst + (size_t)m * KEXP + c4;
    *(ushort4*)(d)        = hi;
    *(ushort4*)(d + 768)  = lo;
    *(ushort4*)(d + 1536) = hi;
}

// ---------------------------------------------------------------------------
// gemm_qkv: global_load_lds staging, double-buffered LDS, 1 barrier/iter.
// ---------------------------------------------------------------------------
__global__ __launch_bounds__(256) void gemm_qkv_kernel(
    const unsigned short* __restrict__ A, const unsigned short* __restrict__ Bm,
    unsigned short* __restrict__ qe, unsigned short* __restrict__ ke,
    unsigned short* __restrict__ vtp)
{
    __shared__ unsigned short AsF[2*128*32];
    __shared__ unsigned short BsF[2*128*32];
    int mi, ni;
    gemm_decode(blockIdx.x, 18, mi, ni);
    const int n0 = ni * 128;
    const int m0 = mi * 128;
    const int t = threadIdx.x;
    const int lane = t & 63, wv = t >> 6;
    const int wr = wv >> 1, wc = wv & 1;
    const int q4 = lane >> 4, r = lane & 15;
    const int lrr = lane >> 2;            // row-within-16 group
    const int lcc = (lane & 3) * 8;       // k-chunk

    f32x4 acc[4][4];
    #pragma unroll
    for (int i = 0; i < 4; i++)
        #pragma unroll
        for (int j = 0; j < 4; j++)
            #pragma unroll
            for (int e = 0; e < 4; e++) acc[i][j][e] = 0.f;

    const unsigned short* gA = A  + (size_t)(m0 + wv*16 + lrr) * KEXP + lcc;
    const unsigned short* gB = Bm + (size_t)(n0 + wv*16 + lrr) * KEXP + lcc;

    // prologue: tile kb=0 into buffer 0
    gl2lds16(gA, AsF + wv*512);
    gl2lds16(gA + (size_t)64 * KEXP, AsF + 2048 + wv*512);
    gl2lds16(gB, BsF + wv*512);
    gl2lds16(gB + (size_t)64 * KEXP, BsF + 2048 + wv*512);

    int pb = 0;
    for (int kb = 0; kb < KEXP; kb += 32) {
        __syncthreads();   // drains prefetch (tile kb ready) + prev ds_reads
        if (kb + 32 < KEXP) {
            int o = (pb ^ 1) * 4096;
            gl2lds16(gA + kb + 32, AsF + o + wv*512);
            gl2lds16(gA + kb + 32 + (size_t)64 * KEXP, AsF + o + 2048 + wv*512);
            gl2lds16(gB + kb + 32, BsF + o + wv*512);
            gl2lds16(gB + kb + 32 + (size_t)64 * KEXP, BsF + o + 2048 + wv*512);
        }
        const int cbuf = pb * 4096;
        s16x8 af[4], bfr[4];
        #pragma unroll
        for (int i = 0; i < 4; i++) {
            af[i]  = *(const s16x8*)&AsF[cbuf + (wr*64 + i*16 + r)*32 + q4*8];
            bfr[i] = *(const s16x8*)&BsF[cbuf + (wc*64 + i*16 + r)*32 + q4*8];
        }
        #pragma unroll
        for (int i = 0; i < 4; i++)
            #pragma unroll
            for (int j = 0; j < 4; j++)
                acc[i][j] = __builtin_amdgcn_mfma_f32_16x16x32_bf16(af[i], bfr[j], acc[i][j], 0, 0, 0);
        pb ^= 1;
    }

    const int sel = n0 / C_;
    const int off = n0 % C_;
    const float scl = (sel == 0) ? 0.125f : 1.0f;
    #pragma unroll
    for (int i = 0; i < 4; i++) {
        #pragma unroll
        for (int rr = 0; rr < 4; rr++) {
            int gm = m0 + wr*64 + i*16 + q4*4 + rr;
            if (gm < M_TOT) {
                int bb = gm / N_, n = gm - bb * N_;
                #pragma unroll
                for (int j = 0; j < 4; j++) {
                    int col = off + wc*64 + j*16 + r;
                    int h = col >> 6, d = col & 63;
                    float val = acc[i][j][rr] * scl;
                    unsigned short hi = f2bf(val);
                    unsigned short lo = f2bf(val - bf2f(hi));
                    size_t bh = (size_t)(bb*H_ + h);
                    if (sel <= 1) {
                        unsigned short* dst = (sel == 0 ? qe : ke) + (bh*NPAD + n)*128;
                        dst[d]      = hi;
                        dst[64 + d] = lo;
                    } else {
                        unsigned short* dst = vtp + bh*128*NPAD;
                        dst[(size_t)d*NPAD + n]        = hi;
                        dst[(size_t)(64 + d)*NPAD + n] = lo;
                    }
                }
            }
        }
    }
}

__global__ __launch_bounds__(256) void gemm_out_kernel(
    const unsigned short* __restrict__ A, const unsigned short* __restrict__ Bm,
    const float* __restrict__ bias, float* __restrict__ out)
{
    __shared__ unsigned short AsF[2*128*32];
    __shared__ unsigned short BsF[2*128*32];
    int mi, ni;
    gemm_decode(blockIdx.x, 6, mi, ni);
    const int n0 = ni * 128;
    const int m0 = mi * 128;
    const int t = threadIdx.x;
    const int lane = t & 63, wv = t >> 6;
    const int wr = wv >> 1, wc = wv & 1;
    const int q4 = lane >> 4, r = lane & 15;
    const int lrr = lane >> 2;
    const int lcc = (lane & 3) * 8;

    f32x4 acc[4][4];
    #pragma unroll
    for (int i = 0; i < 4; i++)
        #pragma unroll
        for (int j = 0; j < 4; j++)
            #pragma unroll
            for (int e = 0; e < 4; e++) acc[i][j][e] = 0.f;

    const unsigned short* gA = A  + (size_t)(m0 + wv*16 + lrr) * KEXP + lcc;
    const unsigned short* gB = Bm + (size_t)(n0 + wv*16 + lrr) * KEXP + lcc;

    gl2lds16(gA, AsF + wv*512);
    gl2lds16(gA + (size_t)64 * KEXP, AsF + 2048 + wv*512);
    gl2lds16(gB, BsF + wv*512);
    gl2lds16(gB + (size_t)64 * KEXP, BsF + 2048 + wv*512);

    int pb = 0;
    for (int kb = 0; kb < KEXP; kb += 32) {
        __syncthreads();
        if (kb + 32 < KEXP) {
            int o = (pb ^ 1) * 4096;
            gl2lds16(gA + kb + 32, AsF + o + wv*512);
            gl2lds16(gA + kb + 32 + (size_t)64 * KEXP, AsF + o + 2048 + wv*512);
            gl2lds16(gB + kb + 32, BsF + o + wv*512);
            gl2lds16(gB + kb + 32 + (size_t)64 * KEXP, BsF + o + 2048 + wv*512);
        }
        const int cbuf = pb * 4096;
        s16x8 af[4], bfr[4];
        #pragma unroll
        for (int i = 0; i < 4; i++) {
            af[i]  = *(const s16x8*)&AsF[cbuf + (wr*64 + i*16 + r)*32 + q4*8];
            bfr[i] = *(const s16x8*)&BsF[cbuf + (wc*64 + i*16 + r)*32 + q4*8];
        }
        #pragma unroll
        for (int i = 0; i < 4; i++)
            #pragma unroll
            for (int j = 0; j < 4; j++)
                acc[i][j] = __builtin_amdgcn_mfma_f32_16x16x32_bf16(af[i], bfr[j], acc[i][j], 0, 0, 0);
        pb ^= 1;
    }

    #pragma unroll
    for (int i = 0; i < 4; i++) {
        #pragma unroll
        for (int rr = 0; rr < 4; rr++) {
            int gm = m0 + wr*64 + i*16 + q4*4 + rr;
            if (gm < M_TOT) {
                #pragma unroll
                for (int j = 0; j < 4; j++) {
                    int col = n0 + wc*64 + j*16 + r;
                    out[(size_t)gm * C_ + col] = acc[i][j][rr] + bias[col];
                }
            }
        }
    }
}

// ---------------------------------------------------------------------------
// MFMA flash attention (r10/r12, passing): XCD-grouped 1D grid.
// ---------------------------------------------------------------------------
__global__ __launch_bounds__(256) void attn_kernel(
    const unsigned short* __restrict__ qe, const unsigned short* __restrict__ ke,
    const unsigned short* __restrict__ vtp, unsigned short* __restrict__ ctxs)
{
    __shared__ unsigned short Qe[64][136];
    __shared__ unsigned short KP[64][136];
    __shared__ unsigned short Vt[64][136];

    const int qt = blockIdx.x / 48;
    const int g  = blockIdx.x - qt * 48;
    const int h = g % 12, b = g / 12;
    const int t = threadIdx.x;
    const int w = t >> 6, lane = t & 63;
    const int quad = lane >> 4, r16 = lane & 15;
    const int q8 = quad * 8;
    const size_t bh = (size_t)(b*H_ + h);

    {
        const unsigned short* src = qe + (bh*NPAD + qt*64 + (t >> 2)) * 128;
        #pragma unroll
        for (int e = 0; e < 4; e++) {
            int c = ((t & 3) + 4*e) * 8;
            *(uint4*)&Qe[t >> 2][c] = *(const uint4*)(src + c);
        }
    }

    int qu;
    {
        int rlo = qt*64, rhi = min(qt*64 + 63, N_ - 1);
        if (rlo == 0) qu = -2;
        else { int b1 = (rlo-1)>>8, b2 = (rhi-1)>>8; qu = (b1==b2) ? b1 : -2; }
    }

    float m_run[4], l_run[4];
    f32x4 ctx[4];
    #pragma unroll
    for (int i = 0; i < 4; i++) {
        m_run[i] = -1e30f; l_run[i] = 0.f;
        #pragma unroll
        for (int e = 0; e < 4; e++) ctx[i][e] = 0.f;
    }

    for (int kt = 0; kt < 17; kt++) {
        if (qu >= 0 && kt > 0) {
            int clo = kt*64, chi = min(kt*64 + 63, N_ - 1);
            int b1 = (clo-1)>>8, b2 = (chi-1)>>8;
            if (b1 == b2 && b1 == qu) continue;
        }

        __syncthreads();
        {
            const unsigned short* ksrc = ke + (bh*NPAD + kt*64 + (t >> 2)) * 128;
            #pragma unroll
            for (int e = 0; e < 4; e++) {
                int c = ((t & 3) + 4*e) * 8;
                *(uint4*)&KP[t >> 2][c] = *(const uint4*)(ksrc + c);
            }
            const int p = t >> 1;
            const unsigned short* vsrc = vtp + (bh*128 + p)*NPAD + kt*64;
            const int vd = p & 63, vseg = (p >> 6) * 64;
            #pragma unroll
            for (int e = 0; e < 4; e++) {
                int c = ((t & 1) + 2*e) * 8;
                *(uint4*)&Vt[vd][vseg + c] = *(const uint4*)(vsrc + c);
            }
        }
        __syncthreads();

        f32x4 st[4];
        #pragma unroll
        for (int j = 0; j < 4; j++)
            #pragma unroll
            for (int e = 0; e < 4; e++) st[j][e] = 0.f;
        {
            const int ar = w*16 + r16;
            s16x8 ah0 = *(const s16x8*)&Qe[ar][q8];
            s16x8 ah1 = *(const s16x8*)&Qe[ar][32 + q8];
            s16x8 al0 = *(const s16x8*)&Qe[ar][64 + q8];
            s16x8 al1 = *(const s16x8*)&Qe[ar][96 + q8];
            #pragma unroll
            for (int j = 0; j < 4; j++) {
                const int br = j*16 + r16;
                s16x8 bh0 = *(const s16x8*)&KP[br][q8];
                s16x8 bh1 = *(const s16x8*)&KP[br][32 + q8];
                s16x8 bl0 = *(const s16x8*)&KP[br][64 + q8];
                s16x8 bl1 = *(const s16x8*)&KP[br][96 + q8];
                st[j] = __builtin_amdgcn_mfma_f32_16x16x32_bf16(ah0, bh0, st[j], 0,0,0);
                st[j] = __builtin_amdgcn_mfma_f32_16x16x32_bf16(ah1, bh1, st[j], 0,0,0);
                st[j] = __builtin_amdgcn_mfma_f32_16x16x32_bf16(ah0, bl0, st[j], 0,0,0);
                st[j] = __builtin_amdgcn_mfma_f32_16x16x32_bf16(ah1, bl1, st[j], 0,0,0);
                st[j] = __builtin_amdgcn_mfma_f32_16x16x32_bf16(al0, bh0, st[j], 0,0,0);
                st[j] = __builtin_amdgcn_mfma_f32_16x16x32_bf16(al1, bh1, st[j], 0,0,0);
            }
        }

        float pv[4][4];
        float alpha[4];
        #pragma unroll
        for (int reg = 0; reg < 4; reg++) {
            int gr = qt*64 + w*16 + quad*4 + reg;
            int qb = (gr >= 1) ? ((gr - 1) >> 8) : -1;
            float mx = -1e30f;
            float vv[4];
            #pragma unroll
            for (int j = 0; j < 4; j++) {
                int gc = kt*64 + j*16 + r16;
                bool ok = (gr < N_) && (gc < N_) &&
                          !((gr >= 1) && (gc >= 1) && (((gc - 1) >> 8) == qb));
                vv[j] = ok ? st[j][reg] : -1e30f;
                mx = fmaxf(mx, vv[j]);
            }
            mx = fmaxf(mx, __shfl_xor(mx, 1));
            mx = fmaxf(mx, __shfl_xor(mx, 2));
            mx = fmaxf(mx, __shfl_xor(mx, 4));
            mx = fmaxf(mx, __shfl_xor(mx, 8));
            float mnew = fmaxf(m_run[reg], mx);
            alpha[reg] = __expf(m_run[reg] - mnew);
            m_run[reg] = mnew;
            float ps = 0.f;
            #pragma unroll
            for (int j = 0; j < 4; j++) {
                float pp = (vv[j] > -1e29f) ? __expf(vv[j] - mnew) : 0.f;
                pv[reg][j] = pp; ps += pp;
            }
            ps += __shfl_xor(ps, 1);
            ps += __shfl_xor(ps, 2);
            ps += __shfl_xor(ps, 4);
            ps += __shfl_xor(ps, 8);
            l_run[reg] = l_run[reg] * alpha[reg] + ps;
        }

        __syncthreads();

        #pragma unroll
        for (int reg = 0; reg < 4; reg++) {
            int lrow = w*16 + quad*4 + reg;
            #pragma unroll
            for (int j = 0; j < 4; j++) {
                float pp = pv[reg][j];
                unsigned short ph = f2bf(pp);
                unsigned short pl = f2bf(pp - bf2f(ph));
                KP[lrow][j*16 + r16]      = ph;
                KP[lrow][64 + j*16 + r16] = pl;
            }
        }

        #pragma unroll
        for (int nj = 0; nj < 4; nj++)
            #pragma unroll
            for (int reg = 0; reg < 4; reg++)
                ctx[nj][reg] *= alpha[reg];

        {
            const int ar = w*16 + r16;
            s16x8 ph0 = *(const s16x8*)&KP[ar][q8];
            s16x8 ph1 = *(const s16x8*)&KP[ar][32 + q8];
            s16x8 pl0 = *(const s16x8*)&KP[ar][64 + q8];
            s16x8 pl1 = *(const s16x8*)&KP[ar][96 + q8];
            #pragma unroll
            for (int nj = 0; nj < 4; nj++) {
                const int br = nj*16 + r16;
                s16x8 vh0 = *(const s16x8*)&Vt[br][q8];
                s16x8 vh1 = *(const s16x8*)&Vt[br][32 + q8];
                s16x8 vl0 = *(const s16x8*)&Vt[br][64 + q8];
                s16x8 vl1 = *(const s16x8*)&Vt[br][96 + q8];
                ctx[nj] = __builtin_amdgcn_mfma_f32_16x16x32_bf16(ph0, vh0, ctx[nj], 0,0,0);
                ctx[nj] = __builtin_amdgcn_mfma_f32_16x16x32_bf16(ph1, vh1, ctx[nj], 0,0,0);
                ctx[nj] = __builtin_amdgcn_mfma_f32_16x16x32_bf16(ph0, vl0, ctx[nj], 0,0,0);
                ctx[nj] = __builtin_amdgcn_mfma_f32_16x16x32_bf16(ph1, vl1, ctx[nj], 0,0,0);
                ctx[nj] = __builtin_amdgcn_mfma_f32_16x16x32_bf16(pl0, vh0, ctx[nj], 0,0,0);
                ctx[nj] = __builtin_amdgcn_mfma_f32_16x16x32_bf16(pl1, vh1, ctx[nj], 0,0,0);
            }
        }
    }

    #pragma unroll
    for (int reg = 0; reg < 4; reg++) {
        int gr = qt*64 + w*16 + quad*4 + reg;
        if (gr < N_) {
            float inv = 1.0f / l_run[reg];
            size_t row = (size_t)(b*N_ + gr) * KEXP;
            #pragma unroll
            for (int nj = 0; nj < 4; nj++) {
                float val = ctx[nj][reg] * inv;
                unsigned short hi = f2bf(val);
                unsigned short lo = f2bf(val - bf2f(hi));
                int c = h*64 + nj*16 + r16;
                ctxs[row + c]        = hi;
                ctxs[row + 768 + c]  = hi;
                ctxs[row + 1536 + c] = lo;
            }
        }
    }
}

// ---------------------------------------------------------------------------
// cls fp64 fused: q0 -> ms -> logits -> softmax max/Z per (h,b) block.
// Bit-identical partitions/reductions to the r12 kernels (indices exact).
// ---------------------------------------------------------------------------
__global__ __launch_bounds__(256) void cls_fused_kernel(
    const float* __restrict__ x, const float* __restrict__ w_qkv,
    double* __restrict__ dws)
{
    __shared__ double q0s[64];
    __shared__ double msS[768];
    __shared__ double lgS[1025];
    __shared__ double red[256];
    const int h = blockIdx.x, b = blockIdx.y;
    const int t = threadIdx.x;
    const int w = t >> 6, lane = t & 63;
    const float* x0 = x + (size_t)b * N_ * C_;

    // q0[d] = 0.125 * (x0 . Wq_row(h*64+d)) -- 64-lane strided dot + butterfly
    for (int d = w; d < 64; d += 4) {
        const float* wr = w_qkv + (size_t)(h*64 + d) * C_;
        double s = 0.0;
        #pragma unroll
        for (int i = 0; i < 12; i++) {
            int c = lane + i*64;
            s += (double)x0[c] * (double)wr[c];
        }
        #pragma unroll
        for (int o = 1; o < 64; o <<= 1) s += __shfl_xor(s, o);
        if (lane == 0) q0s[d] = s * 0.125;
    }
    __syncthreads();

    // ms[c] = sum_d q0[d] * Wk[h*64+d, c]
    for (int c = t; c < 768; c += 256) {
        const float* wk = w_qkv + (size_t)(C_ + h*64) * C_ + c;
        double s = 0.0;
        #pragma unroll 8
        for (int d = 0; d < 64; d++) s += q0s[d] * (double)wk[(size_t)d * C_];
        msS[c] = s;
    }
    __syncthreads();

    // lg[j] = x[b,j,:] . ms
    for (int j = w; j < N_; j += 4) {
        const float* xr = x0 + (size_t)j * C_;
        double s = 0.0;
        #pragma unroll
        for (int i = 0; i < 12; i++) {
            int c = lane + i*64;
            s += (double)xr[c] * msS[c];
        }
        #pragma unroll
        for (int o = 1; o < 64; o <<= 1) s += __shfl_xor(s, o);
        if (lane == 0) {
            lgS[j] = s;
            dws[DLG + ((size_t)(b*H_ + h))*1025 + j] = s;
        }
    }
    __syncthreads();

    // softmax max & Z (same strided + tree order as r12 cls_reduce)
    double mloc = -1e300;
    for (int j = t; j < N_; j += 256) mloc = fmax(mloc, lgS[j]);
    red[t] = mloc; __syncthreads();
    for (int o = 128; o > 0; o >>= 1) {
        if (t < o) red[t] = fmax(red[t], red[t+o]);
        __syncthreads();
    }
    double mx = red[0]; __syncthreads();
    double sloc = 0.0;
    for (int j = t; j < N_; j += 256) sloc += exp(lgS[j] - mx);
    red[t] = sloc; __syncthreads();
    for (int o = 128; o > 0; o >>= 1) {
        if (t < o) red[t] += red[t+o];
        __syncthreads();
    }
    if (t == 0) {
        dws[DMX + b*H_ + h] = mx;
        dws[DZ  + b*H_ + h] = red[0];
    }
}

__global__ __launch_bounds__(1024) void cls_final_kernel(
    const double* __restrict__ dws, float* __restrict__ out)
{
    __shared__ double mv[1024];
    __shared__ int eidx[104], fidx[104];
    const int b = blockIdx.x;
    const int t = threadIdx.x;

    double s = 0.0;
    #pragma unroll
    for (int h = 0; h < H_; h++) {
        double mx = dws[DMX + b*H_ + h];
        double Z  = dws[DZ  + b*H_ + h];
        double lg = dws[DLG + ((size_t)(b*H_ + h))*1025 + (t + 1)];
        s += exp(lg - mx) / Z;
    }
    s *= (1.0 / 12.0);
    mv[t] = s;
    out[OFF_CLS + (size_t)b*1024 + t] = (float)s;
    __syncthreads();

    int cd = 0, ca = 0;
    const double v = s;
    for (int j = 0; j < 1024; j++) {
        double u = mv[j];
        bool tie = (u == v) && (j < t);
        cd += (u > v) || tie;
        ca += (u < v) || tie;
    }
    if (cd < 103) eidx[cd] = t;
    if (ca < 103) fidx[ca] = t;
    __syncthreads();

    if (t < 103) {
        out[OFF_EIDX + (size_t)b*103 + t] = (float)eidx[t];
        out[OFF_FIDX + (size_t)b*103 + t] = (float)fidx[t];
    }
    for (int u4 = t*4; u4 < 103*768; u4 += 4096) {
        int e = u4 / 768;
        float ev = (float)eidx[e], fv = (float)fidx[e];
        *(float4*)&out[OFF_EIND + (size_t)b*103*768 + u4] = make_float4(ev, ev, ev, ev);
        *(float4*)&out[OFF_FIND + (size_t)b*103*768 + u4] = make_float4(fv, fv, fv, fv);
    }
}

// ---------------------------------------------------------------------------
extern "C" void kernel_launch(void* const* d_in, const int* in_sizes, int n_in,
                              void* d_out, int out_size, void* d_ws, size_t ws_size,
                              hipStream_t stream)
{
    const float* x     = (const float*)d_in[0];
    const float* w_qkv = (const float*)d_in[1];
    const float* w_out = (const float*)d_in[2];
    const float* b_out = (const float*)d_in[3];
    float* out = (float*)d_out;
    float* ws  = (float*)d_ws;

    double* dws = (double*)(ws + WS_F64);
    unsigned short* xs   = (unsigned short*)(ws + WS_XS);   // x'; later ctx'
    unsigned short* qkvB = (unsigned short*)(ws + WS_QKVB);
    unsigned short* outB = (unsigned short*)(ws + WS_OUTB);
    unsigned short* qe   = (unsigned short*)(ws + WS_QE);
    unsigned short* ke   = (unsigned short*)(ws + WS_KE);
    unsigned short* vtp  = (unsigned short*)(ws + WS_VT);

    split_all_kernel<<<(SPLIT_TOTAL + 255)/256, 256, 0, stream>>>(
        x, w_qkv, w_out, xs, qkvB, outB);

    gemm_qkv_kernel<<<594, 256, 0, stream>>>(xs, qkvB, qe, ke, vtp);
    attn_kernel<<<816, 256, 0, stream>>>(qe, ke, vtp, xs);

    cls_fused_kernel<<<dim3(H_, B_), 256, 0, stream>>>(x, w_qkv, dws);
    cls_final_kernel<<<B_, 1024, 0, stream>>>(dws, out);

    gemm_out_kernel<<<198, 256, 0, stream>>>(xs, outB, b_out, out);
}

// Round 14
// 454.452 us; speedup vs baseline: 1.2948x; 1.2948x over previous
//
#include <hip/hip_runtime.h>

// ---------------------------------------------------------------------------
// SABlock round 14: revert r13's cls fusion (it collapsed cls_logits from
// 4100 blocks to 48 -> 169 us; launches are cheap, parallelism is not).
// Keep r13's double-buffered GEMM K-loops to measure them cleanly this round.
// Base otherwise = round 12 (467 us, passing).
// ---------------------------------------------------------------------------

#define B_  4
#define N_  1025
#define C_  768
#define H_  12
#define D_  64
#define M_TOT (B_ * N_)      // 4100
#define M_PAD 4224           // 33 * 128
#define KEXP 2304            // 3 * 768
#define NPAD 1088            // 17 * 64

#define OFF_EIND 3148800
#define OFF_EIDX 3465216
#define OFF_FIND 3465628
#define OFF_FIDX 3782044
#define OFF_CLS  3782456

// workspace offsets (floats)
#define WS_F64   0
#define WS_XS    196608      // ushort[4224*2304]  x' A-pattern; later ctx'
#define WS_QKVB  5062656     // ushort[2304*2304]
#define WS_OUTB  7716864     // ushort[768*2304]
#define WS_QE    8601600     // ushort[4*12*1088*128]
#define WS_KE    11943936
#define WS_VT    15286272

// double-region layout (indices into double*)
#define DQ0 0
#define DMS 3072
#define DLG 39936
#define DMX 89136
#define DZ  89184

// splitter work partition
#define SPLIT_A_ITEMS (M_PAD * 192)          // 811008
#define SPLIT_B1_ITEMS (2304 * 192)          // 442368
#define SPLIT_B2_ITEMS (768 * 192)           // 147456
#define SPLIT_TOTAL (SPLIT_A_ITEMS + SPLIT_B1_ITEMS + SPLIT_B2_ITEMS)

typedef short s16x8 __attribute__((ext_vector_type(8)));
typedef float f32x4 __attribute__((ext_vector_type(4)));

__device__ inline unsigned short f2bf(float f) {
    unsigned u = __float_as_uint(f);
    u += 0x7FFF + ((u >> 16) & 1);          // RNE to bf16
    return (unsigned short)(u >> 16);
}
__device__ inline float bf2f(unsigned short h) {
    return __uint_as_float(((unsigned)h) << 16);
}

// async global->LDS, 16 bytes/lane; LDS dest = wave-uniform base + lane*16
__device__ __forceinline__ void gl2lds16(const unsigned short* g, unsigned short* l) {
    __builtin_amdgcn_global_load_lds(
        (const __attribute__((address_space(1))) unsigned int*)g,
        (__attribute__((address_space(3))) unsigned int*)l,
        16, 0, 0);
}

// grouped swizzle: 8-wide m super-rows, n fastest inside a super-row
__device__ inline void gemm_decode(int lid, int NT, int& m, int& n) {
    int gi = lid / (8 * NT);
    int r  = lid % (8 * NT);
    int base = gi * 8;
    int gsize = (33 - base < 8) ? (33 - base) : 8;
    n = r / gsize;
    m = base + r % gsize;
}

// ---------------------------------------------------------------------------
// Merged splitter: A-pattern for x, B-pattern for w_qkv and w_out.
// ---------------------------------------------------------------------------
__global__ __launch_bounds__(256) void split_all_kernel(
    const float* __restrict__ x, const float* __restrict__ w_qkv,
    const float* __restrict__ w_out,
    unsigned short* __restrict__ xs, unsigned short* __restrict__ qkvB,
    unsigned short* __restrict__ outB)
{
    int idx = blockIdx.x * 256 + threadIdx.x;
    if (idx < SPLIT_A_ITEMS) {
        int m = idx / 192, c4 = (idx - m * 192) * 4;
        ushort4 hi = make_ushort4(0,0,0,0), lo = hi;
        if (m < M_TOT) {
            float4 f = *(const float4*)&x[(size_t)m * C_ + c4];
            hi.x = f2bf(f.x); hi.y = f2bf(f.y); hi.z = f2bf(f.z); hi.w = f2bf(f.w);
            lo.x = f2bf(f.x - bf2f(hi.x)); lo.y = f2bf(f.y - bf2f(hi.y));
            lo.z = f2bf(f.z - bf2f(hi.z)); lo.w = f2bf(f.w - bf2f(hi.w));
        }
        unsigned short* d = xs + (size_t)m * KEXP + c4;
        *(ushort4*)(d)        = hi;
        *(ushort4*)(d + 768)  = hi;
        *(ushort4*)(d + 1536) = lo;
        return;
    }
    idx -= SPLIT_A_ITEMS;
    const float* src;
    unsigned short* dst;
    if (idx < SPLIT_B1_ITEMS) { src = w_qkv; dst = qkvB; }
    else { idx -= SPLIT_B1_ITEMS; if (idx >= SPLIT_B2_ITEMS) return; src = w_out; dst = outB; }
    int m = idx / 192, c4 = (idx - m * 192) * 4;
    float4 f = *(const float4*)&src[(size_t)m * C_ + c4];
    ushort4 hi, lo;
    hi.x = f2bf(f.x); hi.y = f2bf(f.y); hi.z = f2bf(f.z); hi.w = f2bf(f.w);
    lo.x = f2bf(f.x - bf2f(hi.x)); lo.y = f2bf(f.y - bf2f(hi.y));
    lo.z = f2bf(f.z - bf2f(hi.z)); lo.w = f2bf(f.w - bf2f(hi.w));
    unsigned short* d = dst + (size_t)m * KEXP + c4;
    *(ushort4*)(d)        = hi;
    *(ushort4*)(d + 768)  = lo;
    *(ushort4*)(d + 1536) = hi;
}

// ---------------------------------------------------------------------------
// gemm_qkv: global_load_lds staging, double-buffered LDS, 1 barrier/iter.
// ---------------------------------------------------------------------------
__global__ __launch_bounds__(256) void gemm_qkv_kernel(
    const unsigned short* __restrict__ A, const unsigned short* __restrict__ Bm,
    unsigned short* __restrict__ qe, unsigned short* __restrict__ ke,
    unsigned short* __restrict__ vtp)
{
    __shared__ unsigned short AsF[2*128*32];
    __shared__ unsigned short BsF[2*128*32];
    int mi, ni;
    gemm_decode(blockIdx.x, 18, mi, ni);
    const int n0 = ni * 128;
    const int m0 = mi * 128;
    const int t = threadIdx.x;
    const int lane = t & 63, wv = t >> 6;
    const int wr = wv >> 1, wc = wv & 1;
    const int q4 = lane >> 4, r = lane & 15;
    const int lrr = lane >> 2;            // row-within-16 group
    const int lcc = (lane & 3) * 8;       // k-chunk

    f32x4 acc[4][4];
    #pragma unroll
    for (int i = 0; i < 4; i++)
        #pragma unroll
        for (int j = 0; j < 4; j++)
            #pragma unroll
            for (int e = 0; e < 4; e++) acc[i][j][e] = 0.f;

    const unsigned short* gA = A  + (size_t)(m0 + wv*16 + lrr) * KEXP + lcc;
    const unsigned short* gB = Bm + (size_t)(n0 + wv*16 + lrr) * KEXP + lcc;

    // prologue: tile kb=0 into buffer 0
    gl2lds16(gA, AsF + wv*512);
    gl2lds16(gA + (size_t)64 * KEXP, AsF + 2048 + wv*512);
    gl2lds16(gB, BsF + wv*512);
    gl2lds16(gB + (size_t)64 * KEXP, BsF + 2048 + wv*512);

    int pb = 0;
    for (int kb = 0; kb < KEXP; kb += 32) {
        __syncthreads();   // drains prefetch (tile kb ready) + prev ds_reads
        if (kb + 32 < KEXP) {
            int o = (pb ^ 1) * 4096;
            gl2lds16(gA + kb + 32, AsF + o + wv*512);
            gl2lds16(gA + kb + 32 + (size_t)64 * KEXP, AsF + o + 2048 + wv*512);
            gl2lds16(gB + kb + 32, BsF + o + wv*512);
            gl2lds16(gB + kb + 32 + (size_t)64 * KEXP, BsF + o + 2048 + wv*512);
        }
        const int cbuf = pb * 4096;
        s16x8 af[4], bfr[4];
        #pragma unroll
        for (int i = 0; i < 4; i++) {
            af[i]  = *(const s16x8*)&AsF[cbuf + (wr*64 + i*16 + r)*32 + q4*8];
            bfr[i] = *(const s16x8*)&BsF[cbuf + (wc*64 + i*16 + r)*32 + q4*8];
        }
        #pragma unroll
        for (int i = 0; i < 4; i++)
            #pragma unroll
            for (int j = 0; j < 4; j++)
                acc[i][j] = __builtin_amdgcn_mfma_f32_16x16x32_bf16(af[i], bfr[j], acc[i][j], 0, 0, 0);
        pb ^= 1;
    }

    const int sel = n0 / C_;
    const int off = n0 % C_;
    const float scl = (sel == 0) ? 0.125f : 1.0f;
    #pragma unroll
    for (int i = 0; i < 4; i++) {
        #pragma unroll
        for (int rr = 0; rr < 4; rr++) {
            int gm = m0 + wr*64 + i*16 + q4*4 + rr;
            if (gm < M_TOT) {
                int bb = gm / N_, n = gm - bb * N_;
                #pragma unroll
                for (int j = 0; j < 4; j++) {
                    int col = off + wc*64 + j*16 + r;
                    int h = col >> 6, d = col & 63;
                    float val = acc[i][j][rr] * scl;
                    unsigned short hi = f2bf(val);
                    unsigned short lo = f2bf(val - bf2f(hi));
                    size_t bh = (size_t)(bb*H_ + h);
                    if (sel <= 1) {
                        unsigned short* dst = (sel == 0 ? qe : ke) + (bh*NPAD + n)*128;
                        dst[d]      = hi;
                        dst[64 + d] = lo;
                    } else {
                        unsigned short* dst = vtp + bh*128*NPAD;
                        dst[(size_t)d*NPAD + n]        = hi;
                        dst[(size_t)(64 + d)*NPAD + n] = lo;
                    }
                }
            }
        }
    }
}

__global__ __launch_bounds__(256) void gemm_out_kernel(
    const unsigned short* __restrict__ A, const unsigned short* __restrict__ Bm,
    const float* __restrict__ bias, float* __restrict__ out)
{
    __shared__ unsigned short AsF[2*128*32];
    __shared__ unsigned short BsF[2*128*32];
    int mi, ni;
    gemm_decode(blockIdx.x, 6, mi, ni);
    const int n0 = ni * 128;
    const int m0 = mi * 128;
    const int t = threadIdx.x;
    const int lane = t & 63, wv = t >> 6;
    const int wr = wv >> 1, wc = wv & 1;
    const int q4 = lane >> 4, r = lane & 15;
    const int lrr = lane >> 2;
    const int lcc = (lane & 3) * 8;

    f32x4 acc[4][4];
    #pragma unroll
    for (int i = 0; i < 4; i++)
        #pragma unroll
        for (int j = 0; j < 4; j++)
            #pragma unroll
            for (int e = 0; e < 4; e++) acc[i][j][e] = 0.f;

    const unsigned short* gA = A  + (size_t)(m0 + wv*16 + lrr) * KEXP + lcc;
    const unsigned short* gB = Bm + (size_t)(n0 + wv*16 + lrr) * KEXP + lcc;

    gl2lds16(gA, AsF + wv*512);
    gl2lds16(gA + (size_t)64 * KEXP, AsF + 2048 + wv*512);
    gl2lds16(gB, BsF + wv*512);
    gl2lds16(gB + (size_t)64 * KEXP, BsF + 2048 + wv*512);

    int pb = 0;
    for (int kb = 0; kb < KEXP; kb += 32) {
        __syncthreads();
        if (kb + 32 < KEXP) {
            int o = (pb ^ 1) * 4096;
            gl2lds16(gA + kb + 32, AsF + o + wv*512);
            gl2lds16(gA + kb + 32 + (size_t)64 * KEXP, AsF + o + 2048 + wv*512);
            gl2lds16(gB + kb + 32, BsF + o + wv*512);
            gl2lds16(gB + kb + 32 + (size_t)64 * KEXP, BsF + o + 2048 + wv*512);
        }
        const int cbuf = pb * 4096;
        s16x8 af[4], bfr[4];
        #pragma unroll
        for (int i = 0; i < 4; i++) {
            af[i]  = *(const s16x8*)&AsF[cbuf + (wr*64 + i*16 + r)*32 + q4*8];
            bfr[i] = *(const s16x8*)&BsF[cbuf + (wc*64 + i*16 + r)*32 + q4*8];
        }
        #pragma unroll
        for (int i = 0; i < 4; i++)
            #pragma unroll
            for (int j = 0; j < 4; j++)
                acc[i][j] = __builtin_amdgcn_mfma_f32_16x16x32_bf16(af[i], bfr[j], acc[i][j], 0, 0, 0);
        pb ^= 1;
    }

    #pragma unroll
    for (int i = 0; i < 4; i++) {
        #pragma unroll
        for (int rr = 0; rr < 4; rr++) {
            int gm = m0 + wr*64 + i*16 + q4*4 + rr;
            if (gm < M_TOT) {
                #pragma unroll
                for (int j = 0; j < 4; j++) {
                    int col = n0 + wc*64 + j*16 + r;
                    out[(size_t)gm * C_ + col] = acc[i][j][rr] + bias[col];
                }
            }
        }
    }
}

// ---------------------------------------------------------------------------
// MFMA flash attention (r10/r12, passing): XCD-grouped 1D grid.
// ---------------------------------------------------------------------------
__global__ __launch_bounds__(256) void attn_kernel(
    const unsigned short* __restrict__ qe, const unsigned short* __restrict__ ke,
    const unsigned short* __restrict__ vtp, unsigned short* __restrict__ ctxs)
{
    __shared__ unsigned short Qe[64][136];
    __shared__ unsigned short KP[64][136];
    __shared__ unsigned short Vt[64][136];

    const int qt = blockIdx.x / 48;
    const int g  = blockIdx.x - qt * 48;
    const int h = g % 12, b = g / 12;
    const int t = threadIdx.x;
    const int w = t >> 6, lane = t & 63;
    const int quad = lane >> 4, r16 = lane & 15;
    const int q8 = quad * 8;
    const size_t bh = (size_t)(b*H_ + h);

    {
        const unsigned short* src = qe + (bh*NPAD + qt*64 + (t >> 2)) * 128;
        #pragma unroll
        for (int e = 0; e < 4; e++) {
            int c = ((t & 3) + 4*e) * 8;
            *(uint4*)&Qe[t >> 2][c] = *(const uint4*)(src + c);
        }
    }

    int qu;
    {
        int rlo = qt*64, rhi = min(qt*64 + 63, N_ - 1);
        if (rlo == 0) qu = -2;
        else { int b1 = (rlo-1)>>8, b2 = (rhi-1)>>8; qu = (b1==b2) ? b1 : -2; }
    }

    float m_run[4], l_run[4];
    f32x4 ctx[4];
    #pragma unroll
    for (int i = 0; i < 4; i++) {
        m_run[i] = -1e30f; l_run[i] = 0.f;
        #pragma unroll
        for (int e = 0; e < 4; e++) ctx[i][e] = 0.f;
    }

    for (int kt = 0; kt < 17; kt++) {
        if (qu >= 0 && kt > 0) {
            int clo = kt*64, chi = min(kt*64 + 63, N_ - 1);
            int b1 = (clo-1)>>8, b2 = (chi-1)>>8;
            if (b1 == b2 && b1 == qu) continue;
        }

        __syncthreads();
        {
            const unsigned short* ksrc = ke + (bh*NPAD + kt*64 + (t >> 2)) * 128;
            #pragma unroll
            for (int e = 0; e < 4; e++) {
                int c = ((t & 3) + 4*e) * 8;
                *(uint4*)&KP[t >> 2][c] = *(const uint4*)(ksrc + c);
            }
            const int p = t >> 1;
            const unsigned short* vsrc = vtp + (bh*128 + p)*NPAD + kt*64;
            const int vd = p & 63, vseg = (p >> 6) * 64;
            #pragma unroll
            for (int e = 0; e < 4; e++) {
                int c = ((t & 1) + 2*e) * 8;
                *(uint4*)&Vt[vd][vseg + c] = *(const uint4*)(vsrc + c);
            }
        }
        __syncthreads();

        f32x4 st[4];
        #pragma unroll
        for (int j = 0; j < 4; j++)
            #pragma unroll
            for (int e = 0; e < 4; e++) st[j][e] = 0.f;
        {
            const int ar = w*16 + r16;
            s16x8 ah0 = *(const s16x8*)&Qe[ar][q8];
            s16x8 ah1 = *(const s16x8*)&Qe[ar][32 + q8];
            s16x8 al0 = *(const s16x8*)&Qe[ar][64 + q8];
            s16x8 al1 = *(const s16x8*)&Qe[ar][96 + q8];
            #pragma unroll
            for (int j = 0; j < 4; j++) {
                const int br = j*16 + r16;
                s16x8 bh0 = *(const s16x8*)&KP[br][q8];
                s16x8 bh1 = *(const s16x8*)&KP[br][32 + q8];
                s16x8 bl0 = *(const s16x8*)&KP[br][64 + q8];
                s16x8 bl1 = *(const s16x8*)&KP[br][96 + q8];
                st[j] = __builtin_amdgcn_mfma_f32_16x16x32_bf16(ah0, bh0, st[j], 0,0,0);
                st[j] = __builtin_amdgcn_mfma_f32_16x16x32_bf16(ah1, bh1, st[j], 0,0,0);
                st[j] = __builtin_amdgcn_mfma_f32_16x16x32_bf16(ah0, bl0, st[j], 0,0,0);
                st[j] = __builtin_amdgcn_mfma_f32_16x16x32_bf16(ah1, bl1, st[j], 0,0,0);
                st[j] = __builtin_amdgcn_mfma_f32_16x16x32_bf16(al0, bh0, st[j], 0,0,0);
                st[j] = __builtin_amdgcn_mfma_f32_16x16x32_bf16(al1, bh1, st[j], 0,0,0);
            }
        }

        float pv[4][4];
        float alpha[4];
        #pragma unroll
        for (int reg = 0; reg < 4; reg++) {
            int gr = qt*64 + w*16 + quad*4 + reg;
            int qb = (gr >= 1) ? ((gr - 1) >> 8) : -1;
            float mx = -1e30f;
            float vv[4];
            #pragma unroll
            for (int j = 0; j < 4; j++) {
                int gc = kt*64 + j*16 + r16;
                bool ok = (gr < N_) && (gc < N_) &&
                          !((gr >= 1) && (gc >= 1) && (((gc - 1) >> 8) == qb));
                vv[j] = ok ? st[j][reg] : -1e30f;
                mx = fmaxf(mx, vv[j]);
            }
            mx = fmaxf(mx, __shfl_xor(mx, 1));
            mx = fmaxf(mx, __shfl_xor(mx, 2));
            mx = fmaxf(mx, __shfl_xor(mx, 4));
            mx = fmaxf(mx, __shfl_xor(mx, 8));
            float mnew = fmaxf(m_run[reg], mx);
            alpha[reg] = __expf(m_run[reg] - mnew);
            m_run[reg] = mnew;
            float ps = 0.f;
            #pragma unroll
            for (int j = 0; j < 4; j++) {
                float pp = (vv[j] > -1e29f) ? __expf(vv[j] - mnew) : 0.f;
                pv[reg][j] = pp; ps += pp;
            }
            ps += __shfl_xor(ps, 1);
            ps += __shfl_xor(ps, 2);
            ps += __shfl_xor(ps, 4);
            ps += __shfl_xor(ps, 8);
            l_run[reg] = l_run[reg] * alpha[reg] + ps;
        }

        __syncthreads();

        #pragma unroll
        for (int reg = 0; reg < 4; reg++) {
            int lrow = w*16 + quad*4 + reg;
            #pragma unroll
            for (int j = 0; j < 4; j++) {
                float pp = pv[reg][j];
                unsigned short ph = f2bf(pp);
                unsigned short pl = f2bf(pp - bf2f(ph));
                KP[lrow][j*16 + r16]      = ph;
                KP[lrow][64 + j*16 + r16] = pl;
            }
        }

        #pragma unroll
        for (int nj = 0; nj < 4; nj++)
            #pragma unroll
            for (int reg = 0; reg < 4; reg++)
                ctx[nj][reg] *= alpha[reg];

        {
            const int ar = w*16 + r16;
            s16x8 ph0 = *(const s16x8*)&KP[ar][q8];
            s16x8 ph1 = *(const s16x8*)&KP[ar][32 + q8];
            s16x8 pl0 = *(const s16x8*)&KP[ar][64 + q8];
            s16x8 pl1 = *(const s16x8*)&KP[ar][96 + q8];
            #pragma unroll
            for (int nj = 0; nj < 4; nj++) {
                const int br = nj*16 + r16;
                s16x8 vh0 = *(const s16x8*)&Vt[br][q8];
                s16x8 vh1 = *(const s16x8*)&Vt[br][32 + q8];
                s16x8 vl0 = *(const s16x8*)&Vt[br][64 + q8];
                s16x8 vl1 = *(const s16x8*)&Vt[br][96 + q8];
                ctx[nj] = __builtin_amdgcn_mfma_f32_16x16x32_bf16(ph0, vh0, ctx[nj], 0,0,0);
                ctx[nj] = __builtin_amdgcn_mfma_f32_16x16x32_bf16(ph1, vh1, ctx[nj], 0,0,0);
                ctx[nj] = __builtin_amdgcn_mfma_f32_16x16x32_bf16(ph0, vl0, ctx[nj], 0,0,0);
                ctx[nj] = __builtin_amdgcn_mfma_f32_16x16x32_bf16(ph1, vl1, ctx[nj], 0,0,0);
                ctx[nj] = __builtin_amdgcn_mfma_f32_16x16x32_bf16(pl0, vh0, ctx[nj], 0,0,0);
                ctx[nj] = __builtin_amdgcn_mfma_f32_16x16x32_bf16(pl1, vh1, ctx[nj], 0,0,0);
            }
        }
    }

    #pragma unroll
    for (int reg = 0; reg < 4; reg++) {
        int gr = qt*64 + w*16 + quad*4 + reg;
        if (gr < N_) {
            float inv = 1.0f / l_run[reg];
            size_t row = (size_t)(b*N_ + gr) * KEXP;
            #pragma unroll
            for (int nj = 0; nj < 4; nj++) {
                float val = ctx[nj][reg] * inv;
                unsigned short hi = f2bf(val);
                unsigned short lo = f2bf(val - bf2f(hi));
                int c = h*64 + nj*16 + r16;
                ctxs[row + c]        = hi;
                ctxs[row + 768 + c]  = hi;
                ctxs[row + 1536 + c] = lo;
            }
        }
    }
}

// ---------------------------------------------------------------------------
// cls fp64 path (r12, passing): 4 sharded kernels + rank-based final.
// ---------------------------------------------------------------------------
__global__ __launch_bounds__(256) void cls_q0_kernel(
    const float* __restrict__ x, const float* __restrict__ w_qkv,
    double* __restrict__ dws)
{
    const int t = threadIdx.x;
    const int wg = blockIdx.x * 4 + (t >> 6);
    const int lane = t & 63;
    const int b = wg / 768, rem = wg - b * 768;
    const float* x0 = x + (size_t)b * N_ * C_;
    const float* wr = w_qkv + (size_t)rem * C_;
    double s = 0.0;
    #pragma unroll
    for (int i = 0; i < 12; i++) {
        int c = lane + i*64;
        s += (double)x0[c] * (double)wr[c];
    }
    #pragma unroll
    for (int o = 1; o < 64; o <<= 1) s += __shfl_xor(s, o);
    if (lane == 0) dws[DQ0 + wg] = s * 0.125;
}

__global__ __launch_bounds__(256) void cls_ms_kernel(
    const float* __restrict__ w_qkv, double* __restrict__ dws)
{
    __shared__ double q0s[64];
    const int t = threadIdx.x;
    const int c = blockIdx.x * 256 + t;
    const int h = blockIdx.y, b = blockIdx.z;
    if (t < 64) q0s[t] = dws[DQ0 + (b*H_ + h)*64 + t];
    __syncthreads();
    const float* wk = w_qkv + (size_t)(C_ + h*64) * C_ + c;
    double s = 0.0;
    #pragma unroll 8
    for (int d = 0; d < 64; d++) s += q0s[d] * (double)wk[(size_t)d * C_];
    dws[DMS + ((size_t)(b*H_ + h))*768 + c] = s;
}

__global__ __launch_bounds__(256) void cls_logits_kernel(
    const float* __restrict__ x, double* __restrict__ dws)
{
    __shared__ double xs[768];
    const int j = blockIdx.x, b = blockIdx.y;
    const int t = threadIdx.x;
    const int w = t >> 6, lane = t & 63;
    const float* xr = x + ((size_t)b * N_ + j) * C_;
    for (int c = t; c < C_; c += 256) xs[c] = (double)xr[c];
    __syncthreads();
    for (int hh = 0; hh < 3; hh++) {
        int h = w + hh * 4;
        const double* ms = dws + DMS + ((size_t)(b*H_ + h))*768;
        double s = 0.0;
        #pragma unroll
        for (int i = 0; i < 12; i++) {
            int c = lane + i*64;
            s += xs[c] * ms[c];
        }
        #pragma unroll
        for (int o = 1; o < 64; o <<= 1) s += __shfl_xor(s, o);
        if (lane == 0) dws[DLG + ((size_t)(b*H_ + h))*1025 + j] = s;
    }
}

__global__ __launch_bounds__(256) void cls_reduce_kernel(
    const double* __restrict__ dwsr, double* __restrict__ dws)
{
    __shared__ double red[256];
    const int h = blockIdx.x, b = blockIdx.y;
    const int t = threadIdx.x;
    const double* lg = dwsr + DLG + ((size_t)(b*H_ + h))*1025;
    double mloc = -1e300;
    for (int j = t; j < N_; j += 256) mloc = fmax(mloc, lg[j]);
    red[t] = mloc; __syncthreads();
    for (int o = 128; o > 0; o >>= 1) {
        if (t < o) red[t] = fmax(red[t], red[t+o]);
        __syncthreads();
    }
    double mx = red[0]; __syncthreads();
    double sloc = 0.0;
    for (int j = t; j < N_; j += 256) sloc += exp(lg[j] - mx);
    red[t] = sloc; __syncthreads();
    for (int o = 128; o > 0; o >>= 1) {
        if (t < o) red[t] += red[t+o];
        __syncthreads();
    }
    if (t == 0) {
        dws[DMX + b*H_ + h] = mx;
        dws[DZ  + b*H_ + h] = red[0];
    }
}

__global__ __launch_bounds__(1024) void cls_final_kernel(
    const double* __restrict__ dws, float* __restrict__ out)
{
    __shared__ double mv[1024];
    __shared__ int eidx[104], fidx[104];
    const int b = blockIdx.x;
    const int t = threadIdx.x;

    double s = 0.0;
    #pragma unroll
    for (int h = 0; h < H_; h++) {
        double mx = dws[DMX + b*H_ + h];
        double Z  = dws[DZ  + b*H_ + h];
        double lg = dws[DLG + ((size_t)(b*H_ + h))*1025 + (t + 1)];
        s += exp(lg - mx) / Z;
    }
    s *= (1.0 / 12.0);
    mv[t] = s;
    out[OFF_CLS + (size_t)b*1024 + t] = (float)s;
    __syncthreads();

    int cd = 0, ca = 0;
    const double v = s;
    for (int j = 0; j < 1024; j++) {
        double u = mv[j];
        bool tie = (u == v) && (j < t);
        cd += (u > v) || tie;
        ca += (u < v) || tie;
    }
    if (cd < 103) eidx[cd] = t;
    if (ca < 103) fidx[ca] = t;
    __syncthreads();

    if (t < 103) {
        out[OFF_EIDX + (size_t)b*103 + t] = (float)eidx[t];
        out[OFF_FIDX + (size_t)b*103 + t] = (float)fidx[t];
    }
    for (int u4 = t*4; u4 < 103*768; u4 += 4096) {
        int e = u4 / 768;
        float ev = (float)eidx[e], fv = (float)fidx[e];
        *(float4*)&out[OFF_EIND + (size_t)b*103*768 + u4] = make_float4(ev, ev, ev, ev);
        *(float4*)&out[OFF_FIND + (size_t)b*103*768 + u4] = make_float4(fv, fv, fv, fv);
    }
}

// ---------------------------------------------------------------------------
extern "C" void kernel_launch(void* const* d_in, const int* in_sizes, int n_in,
                              void* d_out, int out_size, void* d_ws, size_t ws_size,
                              hipStream_t stream)
{
    const float* x     = (const float*)d_in[0];
    const float* w_qkv = (const float*)d_in[1];
    const float* w_out = (const float*)d_in[2];
    const float* b_out = (const float*)d_in[3];
    float* out = (float*)d_out;
    float* ws  = (float*)d_ws;

    double* dws = (double*)(ws + WS_F64);
    unsigned short* xs   = (unsigned short*)(ws + WS_XS);   // x'; later ctx'
    unsigned short* qkvB = (unsigned short*)(ws + WS_QKVB);
    unsigned short* outB = (unsigned short*)(ws + WS_OUTB);
    unsigned short* qe   = (unsigned short*)(ws + WS_QE);
    unsigned short* ke   = (unsigned short*)(ws + WS_KE);
    unsigned short* vtp  = (unsigned short*)(ws + WS_VT);

    split_all_kernel<<<(SPLIT_TOTAL + 255)/256, 256, 0, stream>>>(
        x, w_qkv, w_out, xs, qkvB, outB);

    gemm_qkv_kernel<<<594, 256, 0, stream>>>(xs, qkvB, qe, ke, vtp);
    attn_kernel<<<816, 256, 0, stream>>>(qe, ke, vtp, xs);

    cls_q0_kernel<<<768, 256, 0, stream>>>(x, w_qkv, dws);
    cls_ms_kernel<<<dim3(3, H_, B_), 256, 0, stream>>>(w_qkv, dws);
    cls_logits_kernel<<<dim3(N_, B_), 256, 0, stream>>>(x, dws);
    cls_reduce_kernel<<<dim3(H_, B_), 256, 0, stream>>>(dws, dws);
    cls_final_kernel<<<B_, 1024, 0, stream>>>(dws, out);

    gemm_out_kernel<<<198, 256, 0, stream>>>(xs, outB, b_out, out);
}